// Round 11
// baseline (1473.687 us; speedup 1.0000x reference)
//
#include <hip/hip_runtime.h>

#define NQ 64
#define ND 50000
#define NDP 50048              // padded doc rows (391 full 128-panels)
#define MT (NDP + NQ)          // 50112 total rows (docs + pad + queries)
#define QTOK 32
#define DTOK 16
#define EMB 768
#define HID 512

typedef short s16x8 __attribute__((ext_vector_type(8)));
typedef float f32x4 __attribute__((ext_vector_type(4)));

// ---------- bf16 helpers (RNE) ----------
__device__ __forceinline__ unsigned short f2bf(float f) {
    union { float f; unsigned u; } x; x.f = f;
    unsigned r = x.u + 0x7fffu + ((x.u >> 16) & 1u);
    return (unsigned short)(r >> 16);
}
__device__ __forceinline__ float bf2f(unsigned short h) {
    union { unsigned u; float f; } x; x.u = ((unsigned)h) << 16;
    return x.f;
}
__device__ __forceinline__ unsigned packhi2(float a, float b) {
    return (unsigned)f2bf(a) | ((unsigned)f2bf(b) << 16);
}
__device__ __forceinline__ unsigned packlo2(float a, float b) {
    unsigned short ha = f2bf(a), hb = f2bf(b);
    return (unsigned)f2bf(a - bf2f(ha)) | ((unsigned)f2bf(b - bf2f(hb)) << 16);
}

__device__ __forceinline__ void gload_lds16(const void* g, void* l) {
    __builtin_amdgcn_global_load_lds(
        (const __attribute__((address_space(1))) void*)g,
        (__attribute__((address_space(3))) void*)l, 16, 0, 0);
}

// ============ storage layout ============
// Augmented tensors: [rows][2K] = [hi(0..K-1) | lo(0..K-1)] bf16 (side-agnostic).
// Logical GEMM K2 = 3K in regions [hiA*hiB | loA*hiB | hiA*loB]:
//   A k-offset: ka = k0 < 2K ? k0 : k0-2K
//   B k-offset: kb = k0 <  K ? k0 : k0-K
// Rows 0..49999 docs, 50000..50047 pad (garbage, never consumed), 50048..50111 queries.
// LN folded into GEMM3; L2 folded into scores (see round-10 derivation).
// GEMM K-loop: 3-slot LDS rotation with counted s_waitcnt vmcnt(12) — loads for
// tile t issued at iter t-2, waited (counted, not drained) at iter t. Race-free:
// stage(t+2) targets slot (t-1)%3 whose readers all passed the iter-(t-1)
// trailing barrier; per-wave vmcnt(12) precedes the pre-compute barrier.

// ---------------- mean-pool (docs + queries) -> [hi|lo] bf16 [2*EMB] ----------------
__global__ void pool_aug_all(const float* __restrict__ de, const float* __restrict__ qe,
                             ushort* __restrict__ out) {
    int blk = blockIdx.x, t = threadIdx.x;  // 192 threads x 4 floats
    const float* src;
    int T;
    size_t orow;
    if (blk < ND) { src = de + (size_t)blk * DTOK * EMB; T = DTOK; orow = blk; }
    else          { int qr = blk - ND; src = qe + (size_t)qr * QTOK * EMB; T = QTOK; orow = NDP + qr; }
    const float4* ip = (const float4*)src + t;
    float4 a = make_float4(0.f, 0.f, 0.f, 0.f);
    for (int i = 0; i < T; ++i) {
        float4 v = ip[(size_t)i * (EMB / 4)];
        a.x += v.x; a.y += v.y; a.z += v.z; a.w += v.w;
    }
    const float s = 1.0f / (float)T;
    float v0 = a.x * s, v1 = a.y * s, v2 = a.z * s, v3 = a.w * s;
    ushort* base = out + orow * (2 * EMB);
    *(uint2*)(base + t * 4)       = make_uint2(packhi2(v0, v1), packhi2(v2, v3));
    *(uint2*)(base + EMB + t * 4) = make_uint2(packlo2(v0, v1), packlo2(v2, v3));
}

// ---------------- weight convert, 6 segments: W[K][512] -> Wp[512][2K] = [hi|lo] ----------------
__global__ void wconv_all(const float* __restrict__ dW1, const float* __restrict__ qW1,
                          const float* __restrict__ dW2, const float* __restrict__ qW2,
                          const float* __restrict__ pW,
                          const float* __restrict__ dg, const float* __restrict__ qg,
                          ushort* __restrict__ W1p, ushort* __restrict__ QW1p,
                          ushort* __restrict__ W2p, ushort* __restrict__ QW2p,
                          ushort* __restrict__ W3d, ushort* __restrict__ W3q) {
    int n = blockIdx.x, seg = blockIdx.y;
    const float* W; const float* scale = nullptr; ushort* o; int K;
    switch (seg) {
        case 0:  W = dW1; o = W1p;  K = EMB; break;
        case 1:  W = qW1; o = QW1p; K = EMB; break;
        case 2:  W = dW2; o = W2p;  K = HID; break;
        case 3:  W = qW2; o = QW2p; K = HID; break;
        case 4:  W = pW;  o = W3d;  K = HID; scale = dg; break;
        default: W = pW;  o = W3q;  K = HID; scale = qg; break;
    }
    ushort* base = o + (size_t)n * 2 * K;
    for (int k = threadIdx.x; k < K; k += blockDim.x) {
        float v = W[(size_t)k * HID + n];
        if (scale) v *= scale[k];
        unsigned short hi = f2bf(v);
        base[k]     = hi;
        base[K + k] = f2bf(v - bf2f(hi));
    }
}

// ---------------- u/vv prep: u = g@pW, vv = beta@pW + pb (doc & query) ----------------
__global__ void uv_prep(const float* __restrict__ pW, const float* __restrict__ pb,
                        const float* __restrict__ dg, const float* __restrict__ dbe,
                        const float* __restrict__ qg, const float* __restrict__ qbe,
                        float* __restrict__ ud, float* __restrict__ vvd,
                        float* __restrict__ uq, float* __restrict__ vvq) {
    int n = blockIdx.x;  // 512
    float a = 0.f, b = 0.f, c = 0.f, d = 0.f;
    for (int k = threadIdx.x; k < HID; k += 256) {
        float w = pW[(size_t)k * HID + n];
        a += dg[k] * w; b += dbe[k] * w; c += qg[k] * w; d += qbe[k] * w;
    }
    #pragma unroll
    for (int o = 32; o > 0; o >>= 1) {
        a += __shfl_xor(a, o); b += __shfl_xor(b, o);
        c += __shfl_xor(c, o); d += __shfl_xor(d, o);
    }
    __shared__ float red[4][4];
    int wv = threadIdx.x >> 6, ln = threadIdx.x & 63;
    if (ln == 0) { red[wv][0] = a; red[wv][1] = b; red[wv][2] = c; red[wv][3] = d; }
    __syncthreads();
    if (threadIdx.x == 0) {
        float A = 0, B = 0, C = 0, D = 0;
        #pragma unroll
        for (int i = 0; i < 4; ++i) { A += red[i][0]; B += red[i][1]; C += red[i][2]; D += red[i][3]; }
        ud[n] = A; vvd[n] = B + pb[n]; uq[n] = C; vvq[n] = D + pb[n];
    }
}

// ---------------- MFMA GEMM: 128x256 tile, 8 waves, 3-slot counted-vmcnt pipeline ----------------
// MODE 1: relu(acc+bias) -> hi|lo                         (GEMM1)
// MODE 2: raw acc+bias   -> hi|lo + {sum,sumsq} partials  (GEMM2)
// MODE 3: LN-folded: rs*(acc - mu*u) + vv -> hi|lo + norm2 partials  (GEMM3)
template <int MODE>
__global__ __launch_bounds__(512) void mfma_gemm2(const ushort* __restrict__ A,
                                                  const ushort* __restrict__ Bd,
                                                  const ushort* __restrict__ Bq,
                                                  const float* __restrict__ pard,   // bias | u
                                                  const float* __restrict__ parq,
                                                  const float* __restrict__ auxd,   // vv (MODE 3)
                                                  const float* __restrict__ auxq,
                                                  const float2* __restrict__ statsIn,  // sums (MODE 3)
                                                  float2* __restrict__ sumsOut,        // (MODE 2)
                                                  float* __restrict__ normpOut,        // (MODE 3)
                                                  void* __restrict__ out,
                                                  int M, int K) {
    __shared__ ushort As[3][128 * 64];   // 48KB
    __shared__ ushort Bs[3][256 * 64];   // 96KB
    __shared__ float redS[4][128];       // 2KB
    __shared__ float redQ[4][128];       // 2KB
    const int Ks = 2 * K;
    const int bm = blockIdx.x * 128;
    const int bn = blockIdx.y * 256;
    const bool isq = (bm >= NDP);
    const ushort* B = isq ? Bq : Bd;
    const int tid = threadIdx.x;
    const int lane = tid & 63;
    const int wave = tid >> 6;
    const int wr = wave >> 2;
    const int wc = wave & 3;
    const int nt = (3 * K) >> 6;
    f32x4 acc[4][4] = {};

    auto STAGE = [&](int kt, int slot) {
        const int k0 = kt << 6;
        const int ka = (k0 < 2 * K) ? k0 : k0 - 2 * K;
        const int kb = (k0 < K) ? k0 : k0 - K;
        ushort* Asl = &As[slot][0];
        ushort* Bsl = &Bs[slot][0];
        #pragma unroll
        for (int c = 0; c < 2; ++c) {   // A: 16KB
            int idx = c * 512 + tid;
            int row = idx >> 3, s = idx & 7;
            int gr = bm + row; if (gr >= M) gr = M - 1;
            int ks = (s ^ (row & 7)) << 3;
            gload_lds16(A + (size_t)gr * Ks + ka + ks, Asl + idx * 8);
        }
        #pragma unroll
        for (int c = 0; c < 4; ++c) {   // B: 32KB (bn+n <= 511 always valid)
            int idx = c * 512 + tid;
            int n = idx >> 3, s = idx & 7;
            int ks = (s ^ (n & 7)) << 3;
            gload_lds16(B + (size_t)(bn + n) * Ks + kb + ks, Bsl + idx * 8);
        }
    };

    STAGE(0, 0);
    STAGE(1, 1);
    for (int t = 0; t < nt; ++t) {
        if (t + 2 < nt) {
            STAGE(t + 2, (t + 2) % 3);
            asm volatile("s_waitcnt vmcnt(12)" ::: "memory");   // tile t retired (issued t-2)
        } else if (t + 1 < nt) {
            asm volatile("s_waitcnt vmcnt(6)" ::: "memory");
        } else {
            asm volatile("s_waitcnt vmcnt(0)" ::: "memory");
        }
        __builtin_amdgcn_sched_barrier(0);
        __builtin_amdgcn_s_barrier();      // all waves' tile-t DMA visible; reads may begin
        const ushort* Asl = &As[t % 3][0];
        const ushort* Bsl = &Bs[t % 3][0];
        #pragma unroll
        for (int kk = 0; kk < 2; ++kk) {
            const int sp = kk * 4 + (lane >> 4);
            s16x8 a[4], b[4];
            #pragma unroll
            for (int i = 0; i < 4; ++i) {
                int r = wr * 64 + i * 16 + (lane & 15);
                a[i] = *(const s16x8*)(Asl + r * 64 + ((sp ^ (r & 7)) << 3));
            }
            #pragma unroll
            for (int j = 0; j < 4; ++j) {
                int n = wc * 64 + j * 16 + (lane & 15);
                b[j] = *(const s16x8*)(Bsl + n * 64 + ((sp ^ (n & 7)) << 3));
            }
            #pragma unroll
            for (int i = 0; i < 4; ++i)
                #pragma unroll
                for (int j = 0; j < 4; ++j)
                    acc[i][j] = __builtin_amdgcn_mfma_f32_16x16x32_bf16(a[i], b[j], acc[i][j], 0, 0, 0);
        }
        __builtin_amdgcn_sched_barrier(0);
        __builtin_amdgcn_s_barrier();      // reads of slot t%3 complete before its reuse
    }

    // ---- epilogue; C/D layout: col = bn + wc*64 + j*16 + (lane&15); row = bm + wr*64 + i*16 + (lane>>4)*4 + r
    if (MODE == 1 || MODE == 2) {
        const float* bias = isq ? parq : pard;
        float bv[4];
        #pragma unroll
        for (int j = 0; j < 4; ++j) bv[j] = bias[bn + wc * 64 + j * 16 + (lane & 15)];

        if (MODE == 2) {
            #pragma unroll
            for (int i = 0; i < 4; ++i)
                #pragma unroll
                for (int r = 0; r < 4; ++r) {
                    float ps = 0.f, pq = 0.f;
                    #pragma unroll
                    for (int j = 0; j < 4; ++j) {
                        float v = acc[i][j][r] + bv[j];
                        ps += v; pq += v * v;
                    }
                    #pragma unroll
                    for (int o = 1; o < 16; o <<= 1) { ps += __shfl_xor(ps, o); pq += __shfl_xor(pq, o); }
                    if ((lane & 15) == 0) {
                        int rl = wr * 64 + i * 16 + ((lane >> 4) << 2) + r;
                        redS[wc][rl] = ps; redQ[wc][rl] = pq;
                    }
                }
            __syncthreads();
            if (tid < 128) {
                float s = redS[0][tid] + redS[1][tid] + redS[2][tid] + redS[3][tid];
                float q = redQ[0][tid] + redQ[1][tid] + redQ[2][tid] + redQ[3][tid];
                int grow = bm + tid;
                if (grow < M) sumsOut[(size_t)grow * 2 + blockIdx.y] = make_float2(s, q);
            }
        }

        #pragma unroll
        for (int j = 0; j < 4; ++j) {
            int col = bn + wc * 64 + j * 16 + (lane & 15);
            #pragma unroll
            for (int i = 0; i < 4; ++i)
                #pragma unroll
                for (int r = 0; r < 4; ++r) {
                    int grow = bm + wr * 64 + i * 16 + ((lane >> 4) << 2) + r;
                    if (grow >= M) continue;
                    float v = acc[i][j][r] + bv[j];
                    if (MODE == 1) v = fmaxf(v, 0.0f);
                    unsigned short hi = f2bf(v);
                    ushort* op = (ushort*)out + (size_t)grow * (2 * HID);
                    op[col]       = hi;
                    op[HID + col] = f2bf(v - bf2f(hi));
                }
        }
    } else {  // MODE 3
        const float* u  = isq ? parq : pard;
        const float* vv = isq ? auxq : auxd;
        float uj[4], vj[4];
        #pragma unroll
        for (int j = 0; j < 4; ++j) {
            int col = bn + wc * 64 + j * 16 + (lane & 15);
            uj[j] = u[col]; vj[j] = vv[col];
        }
        #pragma unroll
        for (int i = 0; i < 4; ++i)
            #pragma unroll
            for (int r = 0; r < 4; ++r) {
                int grow = bm + wr * 64 + i * 16 + ((lane >> 4) << 2) + r;
                int gsr  = grow < M ? grow : M - 1;
                float2 p0 = statsIn[(size_t)gsr * 2 + 0];
                float2 p1 = statsIn[(size_t)gsr * 2 + 1];
                float s  = p0.x + p1.x, qq = p0.y + p1.y;
                float mu  = s * (1.0f / 512.0f);
                float var = qq * (1.0f / 512.0f) - mu * mu;
                float rs  = rsqrtf(var + 1e-5f);
                float ps = 0.f;
                #pragma unroll
                for (int j = 0; j < 4; ++j) {
                    float val = rs * (acc[i][j][r] - mu * uj[j]) + vj[j];
                    ps += val * val;
                    if (grow < M) {
                        int col = bn + wc * 64 + j * 16 + (lane & 15);
                        unsigned short hi = f2bf(val);
                        ushort* op = (ushort*)out + (size_t)grow * (2 * HID);
                        op[col]       = hi;
                        op[HID + col] = f2bf(val - bf2f(hi));
                    }
                }
                #pragma unroll
                for (int o = 1; o < 16; o <<= 1) ps += __shfl_xor(ps, o);
                if ((lane & 15) == 0) {
                    int rl = wr * 64 + i * 16 + ((lane >> 4) << 2) + r;
                    redS[wc][rl] = ps;
                }
            }
        __syncthreads();
        if (tid < 128) {
            float s = redS[0][tid] + redS[1][tid] + redS[2][tid] + redS[3][tid];
            int grow = bm + tid;
            if (grow < M) normpOut[(size_t)grow * 2 + blockIdx.y] = s;
        }
    }
}

// ---------------- scores MFMA GEMM: A [64][2K] (rows rowOff..), B [ND][2K]; L2 via normp ----------------
__global__ __launch_bounds__(512) void mfma_scores(const ushort* __restrict__ A,
                                                   const ushort* __restrict__ B,
                                                   const float* __restrict__ normp,
                                                   float* __restrict__ out,
                                                   int M, int N_B, int K, long ldo,
                                                   const float* __restrict__ temp, int rowOff) {
    __shared__ ushort As[3][128 * 64];
    __shared__ ushort Bs[3][256 * 64];
    const int Ks = 2 * K;
    const int bm = blockIdx.x * 128;
    const int bn = blockIdx.y * 256;
    const int tid = threadIdx.x;
    const int lane = tid & 63;
    const int wave = tid >> 6;
    const int wr = wave >> 2;
    const int wc = wave & 3;
    const int nt = (3 * K) >> 6;
    f32x4 acc[4][4] = {};

    auto STAGE = [&](int kt, int slot) {
        const int k0 = kt << 6;
        const int ka = (k0 < 2 * K) ? k0 : k0 - 2 * K;
        const int kb = (k0 < K) ? k0 : k0 - K;
        ushort* Asl = &As[slot][0];
        ushort* Bsl = &Bs[slot][0];
        #pragma unroll
        for (int c = 0; c < 2; ++c) {
            int idx = c * 512 + tid;
            int row = idx >> 3, s = idx & 7;
            int gr = bm + row; if (gr >= M) gr = M - 1;
            int ks = (s ^ (row & 7)) << 3;
            gload_lds16(A + (size_t)gr * Ks + ka + ks, Asl + idx * 8);
        }
        #pragma unroll
        for (int c = 0; c < 4; ++c) {
            int idx = c * 512 + tid;
            int n = idx >> 3, s = idx & 7;
            int gn = bn + n; if (gn >= N_B) gn = N_B - 1;
            int ks = (s ^ (n & 7)) << 3;
            gload_lds16(B + (size_t)gn * Ks + kb + ks, Bsl + idx * 8);
        }
    };

    STAGE(0, 0);
    STAGE(1, 1);
    for (int t = 0; t < nt; ++t) {
        if (t + 2 < nt) {
            STAGE(t + 2, (t + 2) % 3);
            asm volatile("s_waitcnt vmcnt(12)" ::: "memory");
        } else if (t + 1 < nt) {
            asm volatile("s_waitcnt vmcnt(6)" ::: "memory");
        } else {
            asm volatile("s_waitcnt vmcnt(0)" ::: "memory");
        }
        __builtin_amdgcn_sched_barrier(0);
        __builtin_amdgcn_s_barrier();
        const ushort* Asl = &As[t % 3][0];
        const ushort* Bsl = &Bs[t % 3][0];
        #pragma unroll
        for (int kk = 0; kk < 2; ++kk) {
            const int sp = kk * 4 + (lane >> 4);
            s16x8 a[4], b[4];
            #pragma unroll
            for (int i = 0; i < 4; ++i) {
                int r = wr * 64 + i * 16 + (lane & 15);
                a[i] = *(const s16x8*)(Asl + r * 64 + ((sp ^ (r & 7)) << 3));
            }
            #pragma unroll
            for (int j = 0; j < 4; ++j) {
                int n = wc * 64 + j * 16 + (lane & 15);
                b[j] = *(const s16x8*)(Bsl + n * 64 + ((sp ^ (n & 7)) << 3));
            }
            #pragma unroll
            for (int i = 0; i < 4; ++i)
                #pragma unroll
                for (int j = 0; j < 4; ++j)
                    acc[i][j] = __builtin_amdgcn_mfma_f32_16x16x32_bf16(a[i], b[j], acc[i][j], 0, 0, 0);
        }
        __builtin_amdgcn_sched_barrier(0);
        __builtin_amdgcn_s_barrier();
    }

    float invT = 1.0f / temp[0];
    float rB[4];
    #pragma unroll
    for (int j = 0; j < 4; ++j) {
        int gcol = bn + wc * 64 + j * 16 + (lane & 15);
        int gc = gcol < N_B ? gcol : N_B - 1;
        float n2 = normp[(size_t)gc * 2] + normp[(size_t)gc * 2 + 1];
        rB[j] = 1.0f / fmaxf(sqrtf(n2), 1e-12f);
    }
    #pragma unroll
    for (int i = 0; i < 4; ++i)
        #pragma unroll
        for (int r = 0; r < 4; ++r) {
            int grow = bm + wr * 64 + i * 16 + ((lane >> 4) << 2) + r;
            int gr = grow < M ? grow : M - 1;
            float n2a = normp[(size_t)(rowOff + gr) * 2] + normp[(size_t)(rowOff + gr) * 2 + 1];
            float rA = 1.0f / fmaxf(sqrtf(n2a), 1e-12f);
            #pragma unroll
            for (int j = 0; j < 4; ++j) {
                int gcol = bn + wc * 64 + j * 16 + (lane & 15);
                if (grow < M && gcol < N_B)
                    out[(size_t)grow * ldo + gcol] = acc[i][j][r] * rA * rB[j] * invT;
            }
        }
}

// ---------------- top-8 per row with lowest-index tie-break ----------------
__global__ __launch_bounds__(256) void topk_kernel(const float* __restrict__ scores,
                                                   float* __restrict__ out_scores,
                                                   int* __restrict__ out_idx, int N) {
    __shared__ float ls[2048];
    __shared__ int   li[2048];
    const int q   = blockIdx.x;
    const int tid = threadIdx.x;
    const float* row = scores + (size_t)q * N;
    float s[8]; int ix[8];
    #pragma unroll
    for (int i = 0; i < 8; ++i) { s[i] = -1e30f; ix[i] = 0x7fffffff; }
    for (int j = tid; j < N; j += 256) {
        float v = row[j];
        if (v > s[7]) {
            s[7] = v; ix[7] = j;
            #pragma unroll
            for (int t = 7; t > 0; --t) {
                bool sw = (s[t] > s[t-1]) || (s[t] == s[t-1] && ix[t] < ix[t-1]);
                if (sw) {
                    float tv = s[t]; s[t] = s[t-1]; s[t-1] = tv;
                    int   ti = ix[t]; ix[t] = ix[t-1]; ix[t-1] = ti;
                }
            }
        }
    }
    #pragma unroll
    for (int i = 0; i < 8; ++i) { ls[tid * 8 + i] = s[i]; li[tid * 8 + i] = ix[i]; }
    __syncthreads();
    for (int w = 64; w >= 1; w >>= 2) {
        if (tid < w) {
            #pragma unroll
            for (int i = 0; i < 8; ++i) { s[i] = -1e30f; ix[i] = 0x7fffffff; }
            #pragma unroll
            for (int c = 0; c < 32; ++c) {
                float v  = ls[tid * 32 + c];
                int   vi = li[tid * 32 + c];
                bool better = (v > s[7]) || (v == s[7] && vi < ix[7]);
                if (better) {
                    s[7] = v; ix[7] = vi;
                    #pragma unroll
                    for (int t = 7; t > 0; --t) {
                        bool sw = (s[t] > s[t-1]) || (s[t] == s[t-1] && ix[t] < ix[t-1]);
                        if (sw) {
                            float tv = s[t]; s[t] = s[t-1]; s[t-1] = tv;
                            int   ti = ix[t]; ix[t] = ix[t-1]; ix[t-1] = ti;
                        }
                    }
                }
            }
        }
        __syncthreads();
        if (tid < w) {
            #pragma unroll
            for (int i = 0; i < 8; ++i) { ls[tid * 8 + i] = s[i]; li[tid * 8 + i] = ix[i]; }
        }
        __syncthreads();
    }
    if (tid < 8) {
        out_scores[(size_t)q * 8 + tid] = ls[tid];
        out_idx[q * 8 + tid]            = li[tid];
    }
}

// ---------------- gather retrieved docs ----------------
__global__ __launch_bounds__(256) void gather_kernel(const float* __restrict__ docs,
                                                     const int* __restrict__ idx,
                                                     float* __restrict__ out) {
    const int b = blockIdx.x;
    const int d = idx[b];
    const float4* src = (const float4*)(docs + (size_t)d * DTOK * EMB);
    float4*       dst = (float4*)(out + (size_t)b * DTOK * EMB);
    for (int i = threadIdx.x; i < DTOK * EMB / 4; i += 256) dst[i] = src[i];
}

extern "C" void kernel_launch(void* const* d_in, const int* in_sizes, int n_in,
                              void* d_out, int out_size, void* d_ws, size_t ws_size,
                              hipStream_t stream) {
    const float* qe   = (const float*)d_in[0];
    const float* de   = (const float*)d_in[1];
    const float* qW1  = (const float*)d_in[2];
    const float* qb1  = (const float*)d_in[3];
    const float* qW2  = (const float*)d_in[4];
    const float* qb2  = (const float*)d_in[5];
    const float* qg   = (const float*)d_in[6];
    const float* qbe  = (const float*)d_in[7];
    const float* dW1  = (const float*)d_in[8];
    const float* db1  = (const float*)d_in[9];
    const float* dW2  = (const float*)d_in[10];
    const float* db2  = (const float*)d_in[11];
    const float* dg   = (const float*)d_in[12];
    const float* dbe  = (const float*)d_in[13];
    const float* pW   = (const float*)d_in[14];
    const float* pb   = (const float*)d_in[15];
    const float* temp = (const float*)d_in[16];

    float* out = (float*)d_out;

    // ---- workspace carve (~260 MB) ----
    char* w = (char*)d_ws;
    float*  scores = (float*)w;                 w += (size_t)NQ * ND * 4;
    ushort* W1p    = (ushort*)w;                w += (size_t)HID * 2 * EMB * 2;
    ushort* W2p    = (ushort*)w;                w += (size_t)HID * 2 * HID * 2;
    ushort* W3d    = (ushort*)w;                w += (size_t)HID * 2 * HID * 2;
    ushort* QW1p   = (ushort*)w;                w += (size_t)HID * 2 * EMB * 2;
    ushort* QW2p   = (ushort*)w;                w += (size_t)HID * 2 * HID * 2;
    ushort* W3q    = (ushort*)w;                w += (size_t)HID * 2 * HID * 2;
    float*  ud     = (float*)w;                 w += HID * 4;
    float*  vvd    = (float*)w;                 w += HID * 4;
    float*  uq     = (float*)w;                 w += HID * 4;
    float*  vvq    = (float*)w;                 w += HID * 4;
    float2* sums   = (float2*)w;                w += (size_t)MT * 2 * 8;
    float*  normp  = (float*)w;                 w += (size_t)MT * 2 * 4;
    int*    tidx   = (int*)w;                   w += 4096;
    ushort* pooled = (ushort*)w;                w += (size_t)MT * 2 * EMB * 2;     // 154 MB
    ushort* h1a    = (ushort*)w;                w += (size_t)MT * 2 * HID * 2;     // 103 MB
    ushort* h2a    = pooled;   // GEMM2 raw output overwrites pooled (dead after GEMM1)
    ushort* Daug   = h1a;      // GEMM3 output overwrites h1a (dead after GEMM2)
    ushort* qaug   = Daug + (size_t)NDP * 2 * HID;   // query rows inside Daug

    const int GM = (MT + 127) / 128;   // 392 row panels (391 doc + 1 query)

    // ---- weight conversion + LN-fold prep (tiny, 2 launches) ----
    wconv_all<<<dim3(512, 6), 256, 0, stream>>>(dW1, qW1, dW2, qW2, pW, dg, qg,
                                                W1p, QW1p, W2p, QW2p, W3d, W3q);
    uv_prep<<<512, 256, 0, stream>>>(pW, pb, dg, dbe, qg, qbe, ud, vvd, uq, vvq);

    // ---- unified doc+query pipeline ----
    pool_aug_all<<<ND + NQ, 192, 0, stream>>>(de, qe, pooled);
    mfma_gemm2<1><<<dim3(GM, 2), 512, 0, stream>>>(pooled, W1p, QW1p, db1, qb1,
                                                   nullptr, nullptr, nullptr, nullptr, nullptr,
                                                   h1a, MT, EMB);
    mfma_gemm2<2><<<dim3(GM, 2), 512, 0, stream>>>(h1a, W2p, QW2p, db2, qb2,
                                                   nullptr, nullptr, nullptr, sums, nullptr,
                                                   h2a, MT, HID);
    mfma_gemm2<3><<<dim3(GM, 2), 512, 0, stream>>>(h2a, W3d, W3q, ud, uq,
                                                   vvd, vvq, sums, nullptr, normp,
                                                   Daug, MT, HID);

    // ---- scores: [64, ND] = (qaug x Daug^T) scaled by rsqrt norms / T ----
    mfma_scores<<<dim3(1, (ND + 255) / 256), 512, 0, stream>>>(qaug, Daug, normp, scores,
                                                               NQ, ND, HID, (long)ND, temp, NDP);

    // ---- top-k + gather ----
    topk_kernel<<<NQ, 256, 0, stream>>>(scores, out, tidx, ND);
    gather_kernel<<<NQ * 8, 256, 0, stream>>>(de, tidx, out + NQ * 8);
}

// Round 12
// 1299.440 us; speedup vs baseline: 1.1341x; 1.1341x over previous
//
#include <hip/hip_runtime.h>

#define NQ 64
#define ND 50000
#define NDP 50048              // padded doc rows (391 full 128-panels)
#define MT (NDP + NQ)          // 50112 total rows (docs + pad + queries)
#define QTOK 32
#define DTOK 16
#define EMB 768
#define HID 512

typedef short s16x8 __attribute__((ext_vector_type(8)));
typedef float f32x4 __attribute__((ext_vector_type(4)));

// ---------- bf16 helpers (RNE) ----------
__device__ __forceinline__ unsigned short f2bf(float f) {
    union { float f; unsigned u; } x; x.f = f;
    unsigned r = x.u + 0x7fffu + ((x.u >> 16) & 1u);
    return (unsigned short)(r >> 16);
}
__device__ __forceinline__ float bf2f(unsigned short h) {
    union { unsigned u; float f; } x; x.u = ((unsigned)h) << 16;
    return x.f;
}
__device__ __forceinline__ unsigned packhi2(float a, float b) {
    return (unsigned)f2bf(a) | ((unsigned)f2bf(b) << 16);
}
__device__ __forceinline__ unsigned packlo2(float a, float b) {
    unsigned short ha = f2bf(a), hb = f2bf(b);
    return (unsigned)f2bf(a - bf2f(ha)) | ((unsigned)f2bf(b - bf2f(hb)) << 16);
}

__device__ __forceinline__ void gload_lds16(const void* g, void* l) {
    __builtin_amdgcn_global_load_lds(
        (const __attribute__((address_space(1))) void*)g,
        (__attribute__((address_space(3))) void*)l, 16, 0, 0);
}

// ============ storage layout ============
// Augmented tensors: [rows][2K] = [hi(0..K-1) | lo(0..K-1)] bf16 (side-agnostic).
// Logical GEMM K2 = 3K in regions [hiA*hiB | loA*hiB | hiA*loB]:
//   A k-offset: ka = k0 < 2K ? k0 : k0-2K
//   B k-offset: kb = k0 <  K ? k0 : k0-K
// Rows 0..49999 docs, 50000..50047 pad (garbage, never consumed), 50048..50111 queries.
// LN folded into GEMM3: y@pW+pb = rs*(h@W') - rs*mu*u + vv,  W'=diag(g)pW, u=g@pW, vv=beta@pW+pb.
// L2 folded into scores: score = (pq.pd) * rsqrt(n2q) * rsqrt(n2d) / T.
// NOTE (round 11 post-mortem): 3-slot counted-vmcnt pipeline (144KB LDS, 1 block/CU)
// regressed 1298->1473; 2-phase loop + __launch_bounds__(512,4) + 2 blocks/CU is the
// proven optimum — cross-block overlap beats explicit pipelining here.

// ---------------- mean-pool (docs + queries) -> [hi|lo] bf16 [2*EMB] ----------------
__global__ void pool_aug_all(const float* __restrict__ de, const float* __restrict__ qe,
                             ushort* __restrict__ out) {
    int blk = blockIdx.x, t = threadIdx.x;  // 192 threads x 4 floats
    const float* src;
    int T;
    size_t orow;
    if (blk < ND) { src = de + (size_t)blk * DTOK * EMB; T = DTOK; orow = blk; }
    else          { int qr = blk - ND; src = qe + (size_t)qr * QTOK * EMB; T = QTOK; orow = NDP + qr; }
    const float4* ip = (const float4*)src + t;
    float4 a = make_float4(0.f, 0.f, 0.f, 0.f);
    for (int i = 0; i < T; ++i) {
        float4 v = ip[(size_t)i * (EMB / 4)];
        a.x += v.x; a.y += v.y; a.z += v.z; a.w += v.w;
    }
    const float s = 1.0f / (float)T;
    float v0 = a.x * s, v1 = a.y * s, v2 = a.z * s, v3 = a.w * s;
    ushort* base = out + orow * (2 * EMB);
    *(uint2*)(base + t * 4)       = make_uint2(packhi2(v0, v1), packhi2(v2, v3));
    *(uint2*)(base + EMB + t * 4) = make_uint2(packlo2(v0, v1), packlo2(v2, v3));
}

// ---------------- weight convert, 6 segments: W[K][512] -> Wp[512][2K] = [hi|lo] ----------------
// seg 4/5 scale rows by dg/qg (LN-gamma folding into pW).
__global__ void wconv_all(const float* __restrict__ dW1, const float* __restrict__ qW1,
                          const float* __restrict__ dW2, const float* __restrict__ qW2,
                          const float* __restrict__ pW,
                          const float* __restrict__ dg, const float* __restrict__ qg,
                          ushort* __restrict__ W1p, ushort* __restrict__ QW1p,
                          ushort* __restrict__ W2p, ushort* __restrict__ QW2p,
                          ushort* __restrict__ W3d, ushort* __restrict__ W3q) {
    int n = blockIdx.x, seg = blockIdx.y;
    const float* W; const float* scale = nullptr; ushort* o; int K;
    switch (seg) {
        case 0:  W = dW1; o = W1p;  K = EMB; break;
        case 1:  W = qW1; o = QW1p; K = EMB; break;
        case 2:  W = dW2; o = W2p;  K = HID; break;
        case 3:  W = qW2; o = QW2p; K = HID; break;
        case 4:  W = pW;  o = W3d;  K = HID; scale = dg; break;
        default: W = pW;  o = W3q;  K = HID; scale = qg; break;
    }
    ushort* base = o + (size_t)n * 2 * K;
    for (int k = threadIdx.x; k < K; k += blockDim.x) {
        float v = W[(size_t)k * HID + n];
        if (scale) v *= scale[k];
        unsigned short hi = f2bf(v);
        base[k]     = hi;
        base[K + k] = f2bf(v - bf2f(hi));
    }
}

// ---------------- u/vv prep: u = g@pW, vv = beta@pW + pb (doc & query) ----------------
__global__ void uv_prep(const float* __restrict__ pW, const float* __restrict__ pb,
                        const float* __restrict__ dg, const float* __restrict__ dbe,
                        const float* __restrict__ qg, const float* __restrict__ qbe,
                        float* __restrict__ ud, float* __restrict__ vvd,
                        float* __restrict__ uq, float* __restrict__ vvq) {
    int n = blockIdx.x;  // 512
    float a = 0.f, b = 0.f, c = 0.f, d = 0.f;
    for (int k = threadIdx.x; k < HID; k += 256) {
        float w = pW[(size_t)k * HID + n];
        a += dg[k] * w; b += dbe[k] * w; c += qg[k] * w; d += qbe[k] * w;
    }
    #pragma unroll
    for (int o = 32; o > 0; o >>= 1) {
        a += __shfl_xor(a, o); b += __shfl_xor(b, o);
        c += __shfl_xor(c, o); d += __shfl_xor(d, o);
    }
    __shared__ float red[4][4];
    int wv = threadIdx.x >> 6, ln = threadIdx.x & 63;
    if (ln == 0) { red[wv][0] = a; red[wv][1] = b; red[wv][2] = c; red[wv][3] = d; }
    __syncthreads();
    if (threadIdx.x == 0) {
        float A = 0, B = 0, C = 0, D = 0;
        #pragma unroll
        for (int i = 0; i < 4; ++i) { A += red[i][0]; B += red[i][1]; C += red[i][2]; D += red[i][3]; }
        ud[n] = A; vvd[n] = B + pb[n]; uq[n] = C; vvq[n] = D + pb[n];
    }
}

// ---------------- MFMA GEMM: 128x256 tile, 8 waves, per-panel weight select ----------------
// MODE 1: relu(acc+bias) -> hi|lo                         (GEMM1)
// MODE 2: raw acc+bias   -> hi|lo + {sum,sumsq} partials  (GEMM2)
// MODE 3: LN-folded: rs*(acc - mu*u) + vv -> hi|lo + norm2 partials  (GEMM3)
template <int MODE>
__global__ __launch_bounds__(512, 4) void mfma_gemm2(const ushort* __restrict__ A,
                                                     const ushort* __restrict__ Bd,
                                                     const ushort* __restrict__ Bq,
                                                     const float* __restrict__ pard,   // bias | u
                                                     const float* __restrict__ parq,
                                                     const float* __restrict__ auxd,   // vv (MODE 3)
                                                     const float* __restrict__ auxq,
                                                     const float2* __restrict__ statsIn,  // sums (MODE 3)
                                                     float2* __restrict__ sumsOut,        // (MODE 2)
                                                     float* __restrict__ normpOut,        // (MODE 3)
                                                     void* __restrict__ out,
                                                     int M, int K) {
    __shared__ ushort As[128 * 64];   // 16KB
    __shared__ ushort Bs[256 * 64];   // 32KB
    __shared__ float redS[4][128];    // 2KB (stats)
    __shared__ float redQ[4][128];    // 2KB
    const int Ks = 2 * K;
    const int bm = blockIdx.x * 128;
    const int bn = blockIdx.y * 256;
    const bool isq = (bm >= NDP);
    const ushort* B = isq ? Bq : Bd;
    const int tid = threadIdx.x;
    const int lane = tid & 63;
    const int wave = tid >> 6;
    const int wr = wave >> 2;
    const int wc = wave & 3;
    f32x4 acc[4][4] = {};

    for (int k0 = 0; k0 < 3 * K; k0 += 64) {
        const int ka = (k0 < 2 * K) ? k0 : k0 - 2 * K;
        const int kb = (k0 < K) ? k0 : k0 - K;
        #pragma unroll
        for (int c = 0; c < 2; ++c) {   // stage A: 16KB
            int idx = c * 512 + tid;
            int row = idx >> 3, s = idx & 7;
            int gr = bm + row; if (gr >= M) gr = M - 1;
            int ks = (s ^ (row & 7)) << 3;
            gload_lds16(A + (size_t)gr * Ks + ka + ks, As + idx * 8);
        }
        #pragma unroll
        for (int c = 0; c < 4; ++c) {   // stage B: 32KB
            int idx = c * 512 + tid;
            int n = idx >> 3, s = idx & 7;
            int ks = (s ^ (n & 7)) << 3;
            gload_lds16(B + (size_t)(bn + n) * Ks + kb + ks, Bs + idx * 8);
        }
        __syncthreads();

        #pragma unroll
        for (int kk = 0; kk < 2; ++kk) {
            const int sp = kk * 4 + (lane >> 4);
            s16x8 a[4], b[4];
            #pragma unroll
            for (int i = 0; i < 4; ++i) {
                int r = wr * 64 + i * 16 + (lane & 15);
                a[i] = *(const s16x8*)(As + r * 64 + ((sp ^ (r & 7)) << 3));
            }
            #pragma unroll
            for (int j = 0; j < 4; ++j) {
                int n = wc * 64 + j * 16 + (lane & 15);
                b[j] = *(const s16x8*)(Bs + n * 64 + ((sp ^ (n & 7)) << 3));
            }
            #pragma unroll
            for (int i = 0; i < 4; ++i)
                #pragma unroll
                for (int j = 0; j < 4; ++j)
                    acc[i][j] = __builtin_amdgcn_mfma_f32_16x16x32_bf16(a[i], b[j], acc[i][j], 0, 0, 0);
        }
        __syncthreads();
    }

    // ---- epilogue; C/D layout: col = bn + wc*64 + j*16 + (lane&15); row = bm + wr*64 + i*16 + (lane>>4)*4 + r
    if (MODE == 1 || MODE == 2) {
        const float* bias = isq ? parq : pard;
        float bv[4];
        #pragma unroll
        for (int j = 0; j < 4; ++j) bv[j] = bias[bn + wc * 64 + j * 16 + (lane & 15)];

        if (MODE == 2) {   // row stats partials (sum, sumsq over this block's 256 cols)
            #pragma unroll
            for (int i = 0; i < 4; ++i)
                #pragma unroll
                for (int r = 0; r < 4; ++r) {
                    float ps = 0.f, pq = 0.f;
                    #pragma unroll
                    for (int j = 0; j < 4; ++j) {
                        float v = acc[i][j][r] + bv[j];
                        ps += v; pq += v * v;
                    }
                    #pragma unroll
                    for (int o = 1; o < 16; o <<= 1) { ps += __shfl_xor(ps, o); pq += __shfl_xor(pq, o); }
                    if ((lane & 15) == 0) {
                        int rl = wr * 64 + i * 16 + ((lane >> 4) << 2) + r;
                        redS[wc][rl] = ps; redQ[wc][rl] = pq;
                    }
                }
            __syncthreads();
            if (tid < 128) {
                float s = redS[0][tid] + redS[1][tid] + redS[2][tid] + redS[3][tid];
                float q = redQ[0][tid] + redQ[1][tid] + redQ[2][tid] + redQ[3][tid];
                int grow = bm + tid;
                if (grow < M) sumsOut[(size_t)grow * 2 + blockIdx.y] = make_float2(s, q);
            }
        }

        #pragma unroll
        for (int j = 0; j < 4; ++j) {
            int col = bn + wc * 64 + j * 16 + (lane & 15);
            #pragma unroll
            for (int i = 0; i < 4; ++i)
                #pragma unroll
                for (int r = 0; r < 4; ++r) {
                    int grow = bm + wr * 64 + i * 16 + ((lane >> 4) << 2) + r;
                    if (grow >= M) continue;
                    float v = acc[i][j][r] + bv[j];
                    if (MODE == 1) v = fmaxf(v, 0.0f);
                    unsigned short hi = f2bf(v);
                    ushort* op = (ushort*)out + (size_t)grow * (2 * HID);
                    op[col]       = hi;
                    op[HID + col] = f2bf(v - bf2f(hi));
                }
        }
    } else {  // MODE 3
        const float* u  = isq ? parq : pard;
        const float* vv = isq ? auxq : auxd;
        float uj[4], vj[4];
        #pragma unroll
        for (int j = 0; j < 4; ++j) {
            int col = bn + wc * 64 + j * 16 + (lane & 15);
            uj[j] = u[col]; vj[j] = vv[col];
        }
        #pragma unroll
        for (int i = 0; i < 4; ++i)
            #pragma unroll
            for (int r = 0; r < 4; ++r) {
                int grow = bm + wr * 64 + i * 16 + ((lane >> 4) << 2) + r;
                int gsr  = grow < M ? grow : M - 1;
                float2 p0 = statsIn[(size_t)gsr * 2 + 0];
                float2 p1 = statsIn[(size_t)gsr * 2 + 1];
                float s  = p0.x + p1.x, qq = p0.y + p1.y;
                float mu  = s * (1.0f / 512.0f);
                float var = qq * (1.0f / 512.0f) - mu * mu;
                float rs  = rsqrtf(var + 1e-5f);
                float ps = 0.f;
                #pragma unroll
                for (int j = 0; j < 4; ++j) {
                    float val = rs * (acc[i][j][r] - mu * uj[j]) + vj[j];
                    ps += val * val;
                    if (grow < M) {
                        int col = bn + wc * 64 + j * 16 + (lane & 15);
                        unsigned short hi = f2bf(val);
                        ushort* op = (ushort*)out + (size_t)grow * (2 * HID);
                        op[col]       = hi;
                        op[HID + col] = f2bf(val - bf2f(hi));
                    }
                }
                #pragma unroll
                for (int o = 1; o < 16; o <<= 1) ps += __shfl_xor(ps, o);
                if ((lane & 15) == 0) {
                    int rl = wr * 64 + i * 16 + ((lane >> 4) << 2) + r;
                    redS[wc][rl] = ps;
                }
            }
        __syncthreads();
        if (tid < 128) {
            float s = redS[0][tid] + redS[1][tid] + redS[2][tid] + redS[3][tid];
            int grow = bm + tid;
            if (grow < M) normpOut[(size_t)grow * 2 + blockIdx.y] = s;
        }
    }
}

// ---------------- scores MFMA GEMM: A [64][2K] (rows rowOff..), B [ND][2K]; L2 applied via normp ----------------
__global__ __launch_bounds__(512, 4) void mfma_scores(const ushort* __restrict__ A,
                                                      const ushort* __restrict__ B,
                                                      const float* __restrict__ normp,
                                                      float* __restrict__ out,
                                                      int M, int N_B, int K, long ldo,
                                                      const float* __restrict__ temp, int rowOff) {
    __shared__ ushort As[128 * 64];
    __shared__ ushort Bs[256 * 64];
    const int Ks = 2 * K;
    const int bm = blockIdx.x * 128;
    const int bn = blockIdx.y * 256;
    const int tid = threadIdx.x;
    const int lane = tid & 63;
    const int wave = tid >> 6;
    const int wr = wave >> 2;
    const int wc = wave & 3;
    f32x4 acc[4][4] = {};

    for (int k0 = 0; k0 < 3 * K; k0 += 64) {
        const int ka = (k0 < 2 * K) ? k0 : k0 - 2 * K;
        const int kb = (k0 < K) ? k0 : k0 - K;
        #pragma unroll
        for (int c = 0; c < 2; ++c) {
            int idx = c * 512 + tid;
            int row = idx >> 3, s = idx & 7;
            int gr = bm + row; if (gr >= M) gr = M - 1;
            int ks = (s ^ (row & 7)) << 3;
            gload_lds16(A + (size_t)gr * Ks + ka + ks, As + idx * 8);
        }
        #pragma unroll
        for (int c = 0; c < 4; ++c) {
            int idx = c * 512 + tid;
            int n = idx >> 3, s = idx & 7;
            int gn = bn + n; if (gn >= N_B) gn = N_B - 1;
            int ks = (s ^ (n & 7)) << 3;
            gload_lds16(B + (size_t)gn * Ks + kb + ks, Bs + idx * 8);
        }
        __syncthreads();

        #pragma unroll
        for (int kk = 0; kk < 2; ++kk) {
            const int sp = kk * 4 + (lane >> 4);
            s16x8 a[4], b[4];
            #pragma unroll
            for (int i = 0; i < 4; ++i) {
                int r = wr * 64 + i * 16 + (lane & 15);
                a[i] = *(const s16x8*)(As + r * 64 + ((sp ^ (r & 7)) << 3));
            }
            #pragma unroll
            for (int j = 0; j < 4; ++j) {
                int n = wc * 64 + j * 16 + (lane & 15);
                b[j] = *(const s16x8*)(Bs + n * 64 + ((sp ^ (n & 7)) << 3));
            }
            #pragma unroll
            for (int i = 0; i < 4; ++i)
                #pragma unroll
                for (int j = 0; j < 4; ++j)
                    acc[i][j] = __builtin_amdgcn_mfma_f32_16x16x32_bf16(a[i], b[j], acc[i][j], 0, 0, 0);
        }
        __syncthreads();
    }

    float invT = 1.0f / temp[0];
    float rB[4];
    #pragma unroll
    for (int j = 0; j < 4; ++j) {
        int gcol = bn + wc * 64 + j * 16 + (lane & 15);
        int gc = gcol < N_B ? gcol : N_B - 1;
        float n2 = normp[(size_t)gc * 2] + normp[(size_t)gc * 2 + 1];
        rB[j] = 1.0f / fmaxf(sqrtf(n2), 1e-12f);
    }
    #pragma unroll
    for (int i = 0; i < 4; ++i)
        #pragma unroll
        for (int r = 0; r < 4; ++r) {
            int grow = bm + wr * 64 + i * 16 + ((lane >> 4) << 2) + r;
            int gr = grow < M ? grow : M - 1;
            float n2a = normp[(size_t)(rowOff + gr) * 2] + normp[(size_t)(rowOff + gr) * 2 + 1];
            float rA = 1.0f / fmaxf(sqrtf(n2a), 1e-12f);
            #pragma unroll
            for (int j = 0; j < 4; ++j) {
                int gcol = bn + wc * 64 + j * 16 + (lane & 15);
                if (grow < M && gcol < N_B)
                    out[(size_t)grow * ldo + gcol] = acc[i][j][r] * rA * rB[j] * invT;
            }
        }
}

// ---------------- top-8 per row with lowest-index tie-break ----------------
__global__ __launch_bounds__(256) void topk_kernel(const float* __restrict__ scores,
                                                   float* __restrict__ out_scores,
                                                   int* __restrict__ out_idx, int N) {
    __shared__ float ls[2048];
    __shared__ int   li[2048];
    const int q   = blockIdx.x;
    const int tid = threadIdx.x;
    const float* row = scores + (size_t)q * N;
    float s[8]; int ix[8];
    #pragma unroll
    for (int i = 0; i < 8; ++i) { s[i] = -1e30f; ix[i] = 0x7fffffff; }
    for (int j = tid; j < N; j += 256) {
        float v = row[j];
        if (v > s[7]) {
            s[7] = v; ix[7] = j;
            #pragma unroll
            for (int t = 7; t > 0; --t) {
                bool sw = (s[t] > s[t-1]) || (s[t] == s[t-1] && ix[t] < ix[t-1]);
                if (sw) {
                    float tv = s[t]; s[t] = s[t-1]; s[t-1] = tv;
                    int   ti = ix[t]; ix[t] = ix[t-1]; ix[t-1] = ti;
                }
            }
        }
    }
    #pragma unroll
    for (int i = 0; i < 8; ++i) { ls[tid * 8 + i] = s[i]; li[tid * 8 + i] = ix[i]; }
    __syncthreads();
    for (int w = 64; w >= 1; w >>= 2) {
        if (tid < w) {
            #pragma unroll
            for (int i = 0; i < 8; ++i) { s[i] = -1e30f; ix[i] = 0x7fffffff; }
            #pragma unroll
            for (int c = 0; c < 32; ++c) {
                float v  = ls[tid * 32 + c];
                int   vi = li[tid * 32 + c];
                bool better = (v > s[7]) || (v == s[7] && vi < ix[7]);
                if (better) {
                    s[7] = v; ix[7] = vi;
                    #pragma unroll
                    for (int t = 7; t > 0; --t) {
                        bool sw = (s[t] > s[t-1]) || (s[t] == s[t-1] && ix[t] < ix[t-1]);
                        if (sw) {
                            float tv = s[t]; s[t] = s[t-1]; s[t-1] = tv;
                            int   ti = ix[t]; ix[t] = ix[t-1]; ix[t-1] = ti;
                        }
                    }
                }
            }
        }
        __syncthreads();
        if (tid < w) {
            #pragma unroll
            for (int i = 0; i < 8; ++i) { ls[tid * 8 + i] = s[i]; li[tid * 8 + i] = ix[i]; }
        }
        __syncthreads();
    }
    if (tid < 8) {
        out_scores[(size_t)q * 8 + tid] = ls[tid];
        out_idx[q * 8 + tid]            = li[tid];
    }
}

// ---------------- gather retrieved docs ----------------
__global__ __launch_bounds__(256) void gather_kernel(const float* __restrict__ docs,
                                                     const int* __restrict__ idx,
                                                     float* __restrict__ out) {
    const int b = blockIdx.x;
    const int d = idx[b];
    const float4* src = (const float4*)(docs + (size_t)d * DTOK * EMB);
    float4*       dst = (float4*)(out + (size_t)b * DTOK * EMB);
    for (int i = threadIdx.x; i < DTOK * EMB / 4; i += 256) dst[i] = src[i];
}

extern "C" void kernel_launch(void* const* d_in, const int* in_sizes, int n_in,
                              void* d_out, int out_size, void* d_ws, size_t ws_size,
                              hipStream_t stream) {
    const float* qe   = (const float*)d_in[0];
    const float* de   = (const float*)d_in[1];
    const float* qW1  = (const float*)d_in[2];
    const float* qb1  = (const float*)d_in[3];
    const float* qW2  = (const float*)d_in[4];
    const float* qb2  = (const float*)d_in[5];
    const float* qg   = (const float*)d_in[6];
    const float* qbe  = (const float*)d_in[7];
    const float* dW1  = (const float*)d_in[8];
    const float* db1  = (const float*)d_in[9];
    const float* dW2  = (const float*)d_in[10];
    const float* db2  = (const float*)d_in[11];
    const float* dg   = (const float*)d_in[12];
    const float* dbe  = (const float*)d_in[13];
    const float* pW   = (const float*)d_in[14];
    const float* pb   = (const float*)d_in[15];
    const float* temp = (const float*)d_in[16];

    float* out = (float*)d_out;

    // ---- workspace carve (~260 MB) ----
    char* w = (char*)d_ws;
    float*  scores = (float*)w;                 w += (size_t)NQ * ND * 4;
    ushort* W1p    = (ushort*)w;                w += (size_t)HID * 2 * EMB * 2;
    ushort* W2p    = (ushort*)w;                w += (size_t)HID * 2 * HID * 2;
    ushort* W3d    = (ushort*)w;                w += (size_t)HID * 2 * HID * 2;
    ushort* QW1p   = (ushort*)w;                w += (size_t)HID * 2 * EMB * 2;
    ushort* QW2p   = (ushort*)w;                w += (size_t)HID * 2 * HID * 2;
    ushort* W3q    = (ushort*)w;                w += (size_t)HID * 2 * HID * 2;
    float*  ud     = (float*)w;                 w += HID * 4;
    float*  vvd    = (float*)w;                 w += HID * 4;
    float*  uq     = (float*)w;                 w += HID * 4;
    float*  vvq    = (float*)w;                 w += HID * 4;
    float2* sums   = (float2*)w;                w += (size_t)MT * 2 * 8;           // 802 KB
    float*  normp  = (float*)w;                 w += (size_t)MT * 2 * 4;           // 401 KB
    int*    tidx   = (int*)w;                   w += 4096;
    ushort* pooled = (ushort*)w;                w += (size_t)MT * 2 * EMB * 2;     // 154 MB
    ushort* h1a    = (ushort*)w;                w += (size_t)MT * 2 * HID * 2;     // 103 MB
    ushort* h2a    = pooled;   // GEMM2 raw output overwrites pooled (dead after GEMM1)
    ushort* Daug   = h1a;      // GEMM3 output overwrites h1a (dead after GEMM2)
    ushort* qaug   = Daug + (size_t)NDP * 2 * HID;   // query rows inside Daug

    const int GM = (MT + 127) / 128;   // 392 row panels (391 doc + 1 query)

    // ---- weight conversion + LN-fold prep (tiny, 2 launches) ----
    wconv_all<<<dim3(512, 6), 256, 0, stream>>>(dW1, qW1, dW2, qW2, pW, dg, qg,
                                                W1p, QW1p, W2p, QW2p, W3d, W3q);
    uv_prep<<<512, 256, 0, stream>>>(pW, pb, dg, dbe, qg, qbe, ud, vvd, uq, vvq);

    // ---- unified doc+query pipeline ----
    pool_aug_all<<<ND + NQ, 192, 0, stream>>>(de, qe, pooled);
    mfma_gemm2<1><<<dim3(GM, 2), 512, 0, stream>>>(pooled, W1p, QW1p, db1, qb1,
                                                   nullptr, nullptr, nullptr, nullptr, nullptr,
                                                   h1a, MT, EMB);
    mfma_gemm2<2><<<dim3(GM, 2), 512, 0, stream>>>(h1a, W2p, QW2p, db2, qb2,
                                                   nullptr, nullptr, nullptr, sums, nullptr,
                                                   h2a, MT, HID);
    mfma_gemm2<3><<<dim3(GM, 2), 512, 0, stream>>>(h2a, W3d, W3q, ud, uq,
                                                   vvd, vvq, sums, nullptr, normp,
                                                   Daug, MT, HID);

    // ---- scores: [64, ND] = (qaug x Daug^T) scaled by rsqrt norms / T ----
    mfma_scores<<<dim3(1, (ND + 255) / 256), 512, 0, stream>>>(qaug, Daug, normp, scores,
                                                               NQ, ND, HID, (long)ND, temp, NDP);

    // ---- top-k + gather ----
    topk_kernel<<<NQ, 256, 0, stream>>>(scores, out, tidx, ND);
    gather_kernel<<<NQ * 8, 256, 0, stream>>>(de, tidx, out + NQ * 8);
}